// Round 9
// baseline (394.491 us; speedup 1.0000x reference)
//
#include <hip/hip_runtime.h>
#include <cstdint>
#include <cstddef>

#define H      640
#define RH     256
#define NE     5
#define NA     40          // NE * rank
#define NTOK   32768
#define SCAL   2.0f        // alpha/rank = 16/8
#define BM     64          // tokens/block = 64 (one token per lane)
#define WPB    8           // waves/block (512 threads); wave w owns cols 32w..32w+31

__device__ __forceinline__ float4 ld4(const float* p) {
    return *reinterpret_cast<const float4*>(p);
}

// ---------------------------------------------------------------------------
// Kernel 1: router (x@W1 -> silu -> @W2 -> softmax -> top2) + low = x@A.
// Scalar-operand GEMM: lane = token, wave = 32 cols. W1/A/b1/W2 accessed at
// wave-uniform addresses (colbase via readfirstlane) -> compiler scalarizes
// to s_load; FMA is v_fmac_f32 vacc, sW1, vx. NO LDS and NO barriers in the
// K-loop; the per-CU LDS pipe (R3/R8's real bottleneck: ~0.1 ds_read/FMA ~
// 216 us) drops out entirely. x read per-lane global dwordx4 per 4k, L1-
// streamed (row stride 2560B; lines reused across k). 512 thr, grid 512 =
// 2 blocks/CU = 16 waves/CU = 4 waves/SIMD covering s_load latency.
// Waves w<5 also accumulate low[e=w] (8 cols, A[e][k][r] scalar-loaded).
// Epilogue: per-lane silu+W2 partials -> LDS cross-wave reduce -> wave 0
// does top-2 and writes route_c/route_idx.
// ---------------------------------------------------------------------------
__global__ __launch_bounds__(512)
void k_router(const float* __restrict__ x, const float* __restrict__ W1,
              const float* __restrict__ b1v, const float* __restrict__ W2,
              const float* __restrict__ b2v, const float* __restrict__ A,
              float* __restrict__ route_c, int* __restrict__ route_idx)
{
    __shared__ float low_lds[BM][NA];          // 10.2 KB
    __shared__ float part_lds[WPB][BM][NE];    // 10.0 KB

    const int tid   = threadIdx.x;
    const int lane  = tid & 63;
    const int w     = __builtin_amdgcn_readfirstlane(tid >> 6);
    const int token = blockIdx.x * BM + lane;
    const int colbase = w * 32;

    const float* xrow   = x + (size_t)token * H;
    const float* w1base = W1 + colbase;              // + k*RH + c  (uniform)
    const bool   hasA   = (w < NE);
    const float* abase  = A + (size_t)w * H * 8;     // A[e=w][k][r] (uniform)

    float acc[32];
    #pragma unroll
    for (int c = 0; c < 32; c++) acc[c] = 0.f;
    float accl[8];
    #pragma unroll
    for (int r = 0; r < 8; r++) accl[r] = 0.f;

    // ---- K-loop: no LDS, no barriers ----
    float4 xv = ld4(xrow);
    for (int k4 = 0; k4 < H; k4 += 4) {
        float4 xn;
        if (k4 + 4 < H) xn = ld4(xrow + k4 + 4);     // prefetch next 4 k
        #pragma unroll
        for (int u = 0; u < 4; u++) {
            const int k = k4 + u;
            const float xk = (u == 0) ? xv.x : (u == 1) ? xv.y
                           : (u == 2) ? xv.z : xv.w;
            const float* wp = w1base + (size_t)k * RH;   // uniform -> s_load
            #pragma unroll
            for (int c = 0; c < 32; c++)
                acc[c] = fmaf(wp[c], xk, acc[c]);
            if (hasA) {
                const float* ap = abase + (size_t)k * 8; // uniform -> s_load
                #pragma unroll
                for (int r = 0; r < 8; r++)
                    accl[r] = fmaf(ap[r], xk, accl[r]);
            }
        }
        xv = xn;
    }

    // ---- publish low values (waves 0..4, 8 cols each) ----
    if (hasA) {
        *reinterpret_cast<float4*>(&low_lds[lane][w * 8 + 0]) =
            *reinterpret_cast<float4*>(&accl[0]);
        *reinterpret_cast<float4*>(&low_lds[lane][w * 8 + 4]) =
            *reinterpret_cast<float4*>(&accl[4]);
    }

    // ---- per-lane silu + partial logits over this wave's 32 cols ----
    float part[NE];
    #pragma unroll
    for (int e = 0; e < NE; e++) part[e] = 0.f;
    #pragma unroll
    for (int c = 0; c < 32; c++) {
        const int col = colbase + c;                 // uniform
        float v = acc[c] + b1v[col];                 // uniform b1 -> s_load
        float s = __fdividef(v, 1.f + __expf(-v));   // silu
        #pragma unroll
        for (int e = 0; e < NE; e++)
            part[e] = fmaf(s, W2[col * NE + e], part[e]);  // uniform W2
    }
    #pragma unroll
    for (int e = 0; e < NE; e++) part_lds[w][lane][e] = part[e];
    __syncthreads();

    // ---- wave 0: cross-wave logit reduce, top-2, route_c write ----
    if (w == 0) {
        float lg[NE];
        #pragma unroll
        for (int e = 0; e < NE; e++) lg[e] = b2v[e];
        #pragma unroll
        for (int ww = 0; ww < WPB; ww++)
            #pragma unroll
            for (int e = 0; e < NE; e++)
                lg[e] += part_lds[ww][lane][e];

        int   i0 = 0;  float m0 = lg[0];
        int   i1 = -1; float m1 = -3.4e38f;
        if (lg[1] > m0) { m1 = m0; i1 = i0; m0 = lg[1]; i0 = 1; } else if (lg[1] > m1) { m1 = lg[1]; i1 = 1; }
        if (lg[2] > m0) { m1 = m0; i1 = i0; m0 = lg[2]; i0 = 2; } else if (lg[2] > m1) { m1 = lg[2]; i1 = 2; }
        if (lg[3] > m0) { m1 = m0; i1 = i0; m0 = lg[3]; i0 = 3; } else if (lg[3] > m1) { m1 = lg[3]; i1 = 3; }
        if (lg[4] > m0) { m1 = m0; i1 = i0; m0 = lg[4]; i0 = 4; } else if (lg[4] > m1) { m1 = lg[4]; i1 = 4; }
        float w1r = __expf(m1 - m0);
        float inv = __fdividef(1.f, 1.f + w1r);
        float c0 = inv * SCAL;
        float c1 = w1r * inv * SCAL;
        const int gt = token;
        #pragma unroll
        for (int r4 = 0; r4 < 2; r4++) {
            float4 v0 = ld4(&low_lds[lane][i0 * 8 + r4 * 4]);
            v0.x *= c0; v0.y *= c0; v0.z *= c0; v0.w *= c0;
            *reinterpret_cast<float4*>(&route_c[(size_t)gt * 16 + r4 * 4]) = v0;
            float4 v1 = ld4(&low_lds[lane][i1 * 8 + r4 * 4]);
            v1.x *= c1; v1.y *= c1; v1.z *= c1; v1.w *= c1;
            *reinterpret_cast<float4*>(&route_c[(size_t)gt * 16 + 8 + r4 * 4]) = v1;
        }
        route_idx[gt * 2 + 0] = i0;
        route_idx[gt * 2 + 1] = i1;
    }
}

// ---------------------------------------------------------------------------
// Kernel 2: out[t] = base[t] + sum_j c[t][j] * Bm_row[idx_j][:]
// All of Bm (40x640 f32 = 102.4 KB) staged in LDS. 512 thr (8 waves), one
// wave per token at a time; grid = 256 blocks * 128 tokens. ~27 us = at the
// 170 MB HBM roofline for base+out traffic -- leave unchanged.
// ---------------------------------------------------------------------------
__global__ __launch_bounds__(512)
void k_combine(const float* __restrict__ base, const float* __restrict__ Bm,
               const float* __restrict__ route_c, const int* __restrict__ route_idx,
               float* __restrict__ out)
{
    __shared__ float bs[NA][H];
    const int tid = threadIdx.x;
    for (int i4 = tid; i4 < NA * H / 4; i4 += 512)
        reinterpret_cast<float4*>(&bs[0][0])[i4] = reinterpret_cast<const float4*>(Bm)[i4];
    __syncthreads();

    const int w    = tid >> 6;
    const int lane = tid & 63;

    for (int it = 0; it < 16; it++) {
        int t = blockIdx.x * 128 + w * 16 + it;
        t = __builtin_amdgcn_readfirstlane(t);
        const int e0 = route_idx[t * 2 + 0];
        const int e1 = route_idx[t * 2 + 1];
        float cc[16];
        #pragma unroll
        for (int q = 0; q < 4; q++)
            *reinterpret_cast<float4*>(&cc[q * 4]) = ld4(route_c + (size_t)t * 16 + q * 4);

        const float* brow0 = &bs[e0 * 8][0];
        const float* brow1 = &bs[e1 * 8][0];
        const float* bp = base + (size_t)t * H;
        float*       op = out  + (size_t)t * H;

        #pragma unroll
        for (int i = 0; i < 2; i++) {
            int h = i * 256 + lane * 4;
            float4 a = ld4(bp + h);
            #pragma unroll
            for (int j = 0; j < 8; j++) {
                float4 bv = *reinterpret_cast<const float4*>(brow0 + j * H + h);
                a.x = fmaf(cc[j], bv.x, a.x); a.y = fmaf(cc[j], bv.y, a.y);
                a.z = fmaf(cc[j], bv.z, a.z); a.w = fmaf(cc[j], bv.w, a.w);
            }
            #pragma unroll
            for (int j = 0; j < 8; j++) {
                float4 bv = *reinterpret_cast<const float4*>(brow1 + j * H + h);
                a.x = fmaf(cc[8 + j], bv.x, a.x); a.y = fmaf(cc[8 + j], bv.y, a.y);
                a.z = fmaf(cc[8 + j], bv.z, a.z); a.w = fmaf(cc[8 + j], bv.w, a.w);
            }
            *reinterpret_cast<float4*>(op + h) = a;
        }
        {
            int h = 512 + lane * 2;
            float2 a = *reinterpret_cast<const float2*>(bp + h);
            #pragma unroll
            for (int j = 0; j < 8; j++) {
                float2 bv = *reinterpret_cast<const float2*>(brow0 + j * H + h);
                a.x = fmaf(cc[j], bv.x, a.x); a.y = fmaf(cc[j], bv.y, a.y);
            }
            #pragma unroll
            for (int j = 0; j < 8; j++) {
                float2 bv = *reinterpret_cast<const float2*>(brow1 + j * H + h);
                a.x = fmaf(cc[8 + j], bv.x, a.x); a.y = fmaf(cc[8 + j], bv.y, a.y);
            }
            *reinterpret_cast<float2*>(op + h) = a;
        }
    }
}

extern "C" void kernel_launch(void* const* d_in, const int* in_sizes, int n_in,
                              void* d_out, int out_size, void* d_ws, size_t ws_size,
                              hipStream_t stream)
{
    const float* x  = (const float*)d_in[0];
    const float* bo = (const float*)d_in[1];
    const float* W1 = (const float*)d_in[2];
    const float* b1 = (const float*)d_in[3];
    const float* W2 = (const float*)d_in[4];
    const float* b2 = (const float*)d_in[5];
    const float* A  = (const float*)d_in[6];
    const float* Bm = (const float*)d_in[7];
    float* out = (float*)d_out;

    float* route_c   = (float*)d_ws;                                   // 32768*16 f32 = 2 MB
    int*   route_idx = (int*)((char*)d_ws + (size_t)NTOK * 16 * 4);    // 32768*2 i32 = 256 KB

    k_router<<<dim3(NTOK / BM), dim3(512), 0, stream>>>(
        x, W1, b1, W2, b2, A, route_c, route_idx);
    k_combine<<<dim3(256), dim3(512), 0, stream>>>(
        bo, Bm, route_c, route_idx, out);
}